// Round 9
// baseline (172.468 us; speedup 1.0000x reference)
//
#include <hip/hip_runtime.h>
#include <cstdint>

typedef float    f32x4 __attribute__((ext_vector_type(4)));
typedef _Float16 f16x8 __attribute__((ext_vector_type(8)));
typedef unsigned int uint32;

// ---------------------------------------------------------------------------
// Workspace (ushort units): two fp16[256][256] arrays (RNE, alpha folded in)
//   [0]      Wn[i][j] = f16(0.5*W[i][j])   (A-operand for Xv update)
//   [65536]  Wt[j][i] = f16(0.5*W[i][j])   (A-operand for Xh update)
// ---------------------------------------------------------------------------

__global__ void HAM_prep_w(const float* __restrict__ W, unsigned short* __restrict__ ws)
{
    int idx = blockIdx.x * 256 + threadIdx.x;          // 0 .. 65535
    int i = idx >> 8, j = idx & 255;
    _Float16 h = (_Float16)(0.5f * W[idx]);            // RNE, rel err <= 2^-12
    unsigned short hb = __builtin_bit_cast(unsigned short, h);
    ws[idx] = hb;
    ws[65536 + j*256 + i] = hb;
}

__device__ __forceinline__ float fast_tanh(float x)
{
    float e = __expf(2.0f * x);
    return 1.0f - __fdividef(2.0f, e + 1.0f);
}

// ---------------------------------------------------------------------------
// 1024 threads = 16 waves; block owns 32 batch rows.
// Waves 0-7: Xv, 32-feature strip each; waves 8-15: Xh likewise.
// aW[2][8] (64 VGPRs) PINNED resident via asm "+v" at every iteration top --
// the compiler cannot rematerialize L2 loads around an asm def. Zero global
// loads inside the loop. Budget: 64 aW + 16 acc + ~40 temps <= 128 (4 w/SIMD).
// LDS: padded row stride 528 B (16B-aligned; dword-stride 132 == 4 mod 32 ->
// 8-bank spread, free 2-way residual) -> ds offsets are base+IMMEDIATE, no
// per-access VALU. g double-buffered (2 x 33 KB), ONE barrier/iter:
//   phase1 writes buf[it&1] | barrier | phase2 reads buf[it&1]; next phase1
//   writes buf[(it+1)&1] - race-free vs stragglers.
// ---------------------------------------------------------------------------

#define ROWB 528                    // LDS row stride, bytes
#define HALF (32 * ROWB)            // 16896 B: one state-half (32 rows)
#define BUFB (2 * HALF)             // 33792 B: one buffer {gv|gh}

__attribute__((amdgpu_waves_per_eu(4, 4)))
__launch_bounds__(1024)
__global__ void HAM_main(const float* __restrict__ xv_in, const float* __restrict__ xh_in,
                         const unsigned short* __restrict__ wsp, const int* __restrict__ miter,
                         float* __restrict__ out)
{
    extern __shared__ char smem[];   // 2 * BUFB = 67584 B
    const int tid  = threadIdx.x;
    const int wid  = tid >> 6;
    const int lane = tid & 63;
    const int li   = lane & 15;      // MFMA m/n index within tile
    const int g    = lane >> 4;      // quarter-wave group (k-chunk)
    const bool isV = (wid < 8);
    const int fbase = (wid & 7) * 32;
    const long b0 = (long)blockIdx.x * 32;

    const float* xin = isV ? xv_in : xh_in;
    const unsigned short* aP = wsp + (isV ? 0 : 65536);
    const int wrHalf = isV ? 0 : HALF;       // my g goes here (within a buffer)
    const int rdHalf = isV ? HALF : 0;       // my GEMM consumes the other half

    // hoisted per-thread LDS bases (all further addressing is immediates)
    const int wbase = li*ROWB + g*8 + fbase*2 + wrHalf;
    const int rbase = li*ROWB + g*16 + rdHalf;

    // ---- preload W strip into registers: aW[2][8] = 64 VGPRs ----
    f16x8 aW[2][8];
    #pragma unroll
    for (int mt = 0; mt < 2; ++mt) {
        const unsigned short* rp = aP + (fbase + mt*16 + li)*256 + g*8;
        #pragma unroll
        for (int kt = 0; kt < 8; ++kt)
            aW[mt][kt] = *(const f16x8*)(rp + kt*32);   // ushort-unit offsets
    }

    // ---- load initial state into accumulators (D-layout) ----
    f32x4 acc[2][2];
    #pragma unroll
    for (int mt = 0; mt < 2; ++mt)
        #pragma unroll
        for (int nt = 0; nt < 2; ++nt) {
            long b = b0 + nt*16 + li;
            int  f = fbase + mt*16 + g*4;
            acc[mt][nt] = *(const f32x4*)(xin + b*256 + f);
        }

    const int iters = *miter;

    for (int it = 0; it < iters; ++it) {
        // pin W fragments: forces residency, forbids L2 rematerialization
        #pragma unroll
        for (int mt = 0; mt < 2; ++mt)
            #pragma unroll
            for (int kt = 0; kt < 8; ++kt)
                asm volatile("" : "+v"(aW[mt][kt]));

        char* buf = smem + (it & 1) * BUFB;
        char* wr  = buf + wbase;
        char* rd  = buf + rbase;

        // ---- phase 1: g = tanh(x) -> fp16 pairs (cvt_pkrtz) -> LDS ----
        #pragma unroll
        for (int mt = 0; mt < 2; ++mt) {
            #pragma unroll
            for (int nt = 0; nt < 2; ++nt) {
                float t0 = fast_tanh(acc[mt][nt][0]);
                float t1 = fast_tanh(acc[mt][nt][1]);
                float t2 = fast_tanh(acc[mt][nt][2]);
                float t3 = fast_tanh(acc[mt][nt][3]);
                uint32 u01 = __builtin_bit_cast(uint32, __builtin_amdgcn_cvt_pkrtz(t0, t1));
                uint32 u23 = __builtin_bit_cast(uint32, __builtin_amdgcn_cvt_pkrtz(t2, t3));
                *(uint2*)(wr + nt*(16*ROWB) + mt*32) = make_uint2(u01, u23);
            }
        }
        __syncthreads();

        // ---- phase 2: x_new = 0.5*x + g_other * (0.5*W) ----
        #pragma unroll
        for (int mt = 0; mt < 2; ++mt)
            #pragma unroll
            for (int nt = 0; nt < 2; ++nt)
                acc[mt][nt] *= 0.5f;

        #pragma unroll
        for (int kt = 0; kt < 8; ++kt) {
            #pragma unroll
            for (int nt = 0; nt < 2; ++nt) {
                f16x8 bH = *(const f16x8*)(rd + nt*(16*ROWB) + kt*64);
                #pragma unroll
                for (int mt = 0; mt < 2; ++mt)
                    acc[mt][nt] = __builtin_amdgcn_mfma_f32_16x16x32_f16(aW[mt][kt], bH, acc[mt][nt], 0, 0, 0);
            }
        }
        // no trailing barrier: next phase-1 writes the OTHER buffer
    }

    // ---- epilogue: out[b] = [tanh(xv), tanh(xh)] ----
    const int colBase = (isV ? 0 : 256) + fbase;
    #pragma unroll
    for (int mt = 0; mt < 2; ++mt) {
        #pragma unroll
        for (int nt = 0; nt < 2; ++nt) {
            long b = b0 + nt*16 + li;
            f32x4 o;
            #pragma unroll
            for (int j = 0; j < 4; ++j) o[j] = fast_tanh(acc[mt][nt][j]);
            *(f32x4*)(out + b*512 + colBase + mt*16 + g*4) = o;
        }
    }
}

extern "C" void kernel_launch(void* const* d_in, const int* in_sizes, int n_in,
                              void* d_out, int out_size, void* d_ws, size_t ws_size,
                              hipStream_t stream)
{
    const float* xv   = (const float*)d_in[0];
    const float* xh   = (const float*)d_in[1];
    const float* W    = (const float*)d_in[2];
    const int* miter  = (const int*)d_in[3];
    float* out        = (float*)d_out;
    unsigned short* ws = (unsigned short*)d_ws;

    const int B = in_sizes[0] / 256;        // 32768

    HAM_prep_w<<<256, 256, 0, stream>>>(W, ws);

    (void)hipFuncSetAttribute((const void*)HAM_main,
                              hipFuncAttributeMaxDynamicSharedMemorySize, 2 * BUFB);
    HAM_main<<<B / 32, 1024, 2 * BUFB, stream>>>(xv, xh, ws, miter, out);
}